// Round 2
// baseline (138.937 us; speedup 1.0000x reference)
//
#include <hip/hip_runtime.h>
#include <hip/hip_bf16.h>
#include <math.h>

// Problem constants
#define BB 4
#define CC 64
#define HH 128
#define WW 128
#define HW 16384
#define CHW (CC*HW)

typedef __bf16 bf16;
typedef __attribute__((ext_vector_type(8))) __bf16 bf16x8;
typedef __attribute__((ext_vector_type(4))) __bf16 bf16x4;
typedef __attribute__((ext_vector_type(4))) float f32x4;
typedef __attribute__((ext_vector_type(4))) unsigned short u16x4;

#define MFMA(a, b, c) __builtin_amdgcn_mfma_f32_16x16x32_bf16((a), (b), (c), 0, 0, 0)

// ---- Pre-kernel: x NCHW -> NHWC bf16 (blocks 0..1023) + weight frags ----
__global__ __launch_bounds__(256) void k_pre(const float* __restrict__ x,
        bf16* __restrict__ xt,
        const float* __restrict__ dw, const float* __restrict__ ow,
        const float* __restrict__ mw,
        bf16* __restrict__ wfd_hi, bf16* __restrict__ wfd_lo,
        bf16* __restrict__ wfo_hi, bf16* __restrict__ wfo_lo) {
    __shared__ float tile[64][65];
    if (blockIdx.x < 1024) {
        int b    = blockIdx.x >> 8;
        int s0   = (blockIdx.x & 255) * 64;
        int lane = threadIdx.x & 63;
        int w    = threadIdx.x >> 6;
        const float* xb = x + (size_t)b * CHW;
        #pragma unroll
        for (int r = 0; r < 16; ++r) {
            int c = w * 16 + r;
            tile[c][lane] = xb[(size_t)c * HW + s0 + lane];
        }
        __syncthreads();
        bf16* xtb = xt + (size_t)b * CHW;
        // vectorized store: each thread packs 8 channels for one spatial s -> 16B store
        #pragma unroll
        for (int it = 0; it < 2; ++it) {
            int task = it * 256 + threadIdx.x;      // 512 tasks: 64 s x 8 ch-chunks
            int s = task >> 3, ch0 = (task & 7) * 8;
            bf16x8 v;
            #pragma unroll
            for (int j = 0; j < 8; ++j) v[j] = (bf16)tile[ch0 + j][s];
            *(bf16x8*)&xtb[(size_t)(s0 + s) * 64 + ch0] = v;
        }
    } else {
        int idx = (blockIdx.x - 1024) * 256 + threadIdx.x;
        if (idx < 36864) {                          // deform frags: 4 nt * 18 ks * 64 lanes * 8
            int j    = idx & 7;
            int lane = (idx >> 3) & 63;
            int ks   = (idx >> 9) % 18;
            int nt   = idx / (512 * 18);
            int n    = nt * 16 + (lane & 15);
            int kglob = ks * 32 + (lane >> 4) * 8 + j;
            int kk = kglob >> 6, c = kglob & 63;    // K-order: k = kk*64 + c
            float w = dw[(n * 64 + c) * 9 + kk];
            bf16 h = (bf16)w;
            wfd_hi[idx] = h;
            wfd_lo[idx] = (bf16)(w - (float)h);
        } else {
            int idx2 = idx - 36864;                 // offmask frags: 2 nt
            int j    = idx2 & 7;
            int lane = (idx2 >> 3) & 63;
            int ks   = (idx2 >> 9) % 18;
            int nt   = idx2 / (512 * 18);
            int ch   = nt * 16 + (lane & 15);
            int kglob = ks * 32 + (lane >> 4) * 8 + j;
            int kk = kglob >> 6, c = kglob & 63;
            float w = 0.0f;
            if (ch < 18)      w = ow[(ch * 64 + c) * 9 + kk];
            else if (ch < 27) w = mw[((ch - 18) * 64 + c) * 9 + kk];
            bf16 h = (bf16)w;
            wfo_hi[idx2] = h;
            wfo_lo[idx2] = (bf16)(w - (float)h);
        }
    }
}

// ---- Fused offmask-conv + deformable conv, wave-independent dataflow ----
// Each wave owns one st (16 positions) end-to-end:
//   B : offset/mask GEMM (M=16 pos, N=27ch, hi+lo)      -> per-wave om LDS
//   C1: 144 bilinear scalar tasks                        -> per-wave samp LDS
//   D : gather directly into A-frags (lane m,g holds ch par*32+g*8.. of pos m)
//       + deform GEMM (M=16 pos, N=64 out, hi-only), all in registers.
// NO __syncthreads anywhere: cross-lane data stays within the wave,
// ordered by s_waitcnt lgkmcnt(0).
__global__ __launch_bounds__(256) void k_fused(const bf16* __restrict__ xt,
        const bf16* __restrict__ wfo_hi, const bf16* __restrict__ wfo_lo,
        const bf16* __restrict__ wfd_hi,
        const float* __restrict__ ob, const float* __restrict__ mb,
        const float* __restrict__ db, float* __restrict__ out) {
    __shared__ __align__(16) float om_s[4 * 27 * 16];          // 6912 B
    __shared__ __align__(8)  bf16 sampw[4 * 144 * 4];          // 4608 B
    __shared__ __align__(8)  unsigned short sampo[4 * 144 * 4];// 4608 B

    // XCD-chunked swizzle (1024 blocks, 8 XCDs, bijective): 128 consecutive
    // position-tiles per XCD -> xt row reuse stays in one L2.
    int bid = (blockIdx.x & 7) * 128 + (blockIdx.x >> 3);
    int pos0 = bid * 64;
    int wo0 = pos0 & 127;
    int ho  = (pos0 >> 7) & 127;
    int b   = pos0 >> 14;
    int t = threadIdx.x, wave = t >> 6, lane = t & 63;
    int m = lane & 15, g = lane >> 4;
    int st = wave;
    const bf16* xtb = xt + (size_t)b * CHW;
    float* omw = om_s + wave * 27 * 16;
    bf16* swv = sampw + wave * 144 * 4;
    unsigned short* sov = sampo + wave * 144 * 4;

    // ---- Phase B: offset/mask GEMM for this wave's 16 positions ----
    {
        f32x4 acc0 = {0.f, 0.f, 0.f, 0.f};
        f32x4 acc1 = {0.f, 0.f, 0.f, 0.f};
        const bf16x8* bh0 = (const bf16x8*)wfo_hi + lane;
        const bf16x8* bl0 = (const bf16x8*)wfo_lo + lane;
        const bf16x8* bh1 = (const bf16x8*)wfo_hi + 18 * 64 + lane;
        const bf16x8* bl1 = (const bf16x8*)wfo_lo + 18 * 64 + lane;
        #pragma unroll
        for (int kk = 0; kk < 9; ++kk) {
            int y  = ho + kk / 3 - 1;
            int xx = wo0 + st * 16 + m + (kk % 3) - 1;
            bf16x8 ae = {};
            bf16x8 ao = {};
            if ((unsigned)y < 128u && (unsigned)xx < 128u) {
                const bf16* bp = xtb + ((size_t)(y * 128 + xx) << 6);
                ae = *(const bf16x8*)(bp + g * 8);
                ao = *(const bf16x8*)(bp + 32 + g * 8);
            }
            int ks0 = 2 * kk, ks1 = 2 * kk + 1;
            acc0 = MFMA(ae, bh0[ks0 * 64], acc0);
            acc0 = MFMA(ae, bl0[ks0 * 64], acc0);
            acc0 = MFMA(ao, bh0[ks1 * 64], acc0);
            acc0 = MFMA(ao, bl0[ks1 * 64], acc0);
            acc1 = MFMA(ae, bh1[ks0 * 64], acc1);
            acc1 = MFMA(ae, bl1[ks0 * 64], acc1);
            acc1 = MFMA(ao, bh1[ks1 * 64], acc1);
            acc1 = MFMA(ao, bl1[ks1 * 64], acc1);
        }
        // lane (m,g) reg r holds om[ch][p_local]: ch=m (acc0) / 16+m (acc1), p_local=g*4+r
        float bias0 = ob[m];
        f32x4 v0;
        #pragma unroll
        for (int r = 0; r < 4; ++r) v0[r] = acc0[r] + bias0;
        *(f32x4*)&omw[m * 16 + g * 4] = v0;
        int ch1 = 16 + m;
        if (ch1 < 27) {
            float bias1 = (ch1 < 18) ? ob[ch1] : mb[ch1 - 18];
            f32x4 v1;
            #pragma unroll
            for (int r = 0; r < 4; ++r) {
                float v = acc1[r] + bias1;
                if (ch1 >= 18) v = 1.0f / (1.0f + __expf(-v));
                v1[r] = v;
            }
            *(f32x4*)&omw[ch1 * 16 + g * 4] = v1;
        }
    }
    asm volatile("s_waitcnt lgkmcnt(0)" ::: "memory");  // wave-local LDS ordering

    // ---- Phase C1: 144 bilinear scalar tasks for this wave ----
    #pragma unroll
    for (int i = 0; i < 3; ++i) {
        int task = i * 64 + lane;
        if (task < 144) {
            int p = task / 9, k = task - p * 9;     // p in [0,16): local position
            float dy = omw[(2 * k) * 16 + p];
            float dx = omw[(2 * k + 1) * 16 + p];
            float mk = omw[(18 + k) * 16 + p];
            float py = (float)(ho - 1 + k / 3) + dy;
            float px = (float)(wo0 + st * 16 + p - 1 + (k % 3)) + dx;
            float y0f = floorf(py), x0f = floorf(px);
            float fy = py - y0f, fx = px - x0f;
            int y0 = (int)y0f, x0 = (int)x0f;
            int y1 = y0 + 1,  x1 = x0 + 1;
            bool vy0 = (unsigned)y0 < 128u, vy1 = (unsigned)y1 < 128u;
            bool vx0 = (unsigned)x0 < 128u, vx1 = (unsigned)x1 < 128u;
            int y0c = min(max(y0, 0), 127), y1c = min(max(y1, 0), 127);
            int x0c = min(max(x0, 0), 127), x1c = min(max(x1, 0), 127);
            bf16x4 wv;
            wv.x = (bf16)((vy0 && vx0) ? mk * (1.f - fy) * (1.f - fx) : 0.f);
            wv.y = (bf16)((vy0 && vx1) ? mk * (1.f - fy) * fx         : 0.f);
            wv.z = (bf16)((vy1 && vx0) ? mk * fy * (1.f - fx)         : 0.f);
            wv.w = (bf16)((vy1 && vx1) ? mk * fy * fx                 : 0.f);
            u16x4 ov;
            ov.x = (unsigned short)(y0c * 128 + x0c);
            ov.y = (unsigned short)(y0c * 128 + x1c);
            ov.z = (unsigned short)(y1c * 128 + x0c);
            ov.w = (unsigned short)(y1c * 128 + x1c);
            *(bf16x4*)&swv[task * 4] = wv;
            *(u16x4*)&sov[task * 4] = ov;
        }
    }
    asm volatile("s_waitcnt lgkmcnt(0)" ::: "memory");  // wave-local LDS ordering

    // ---- Phase D: gather into A-frags in registers + deform GEMM ----
    // MFMA A-frag at ks=2kk+par: lane (m,g) holds val[p=m][kk][c=par*32+g*8+j]
    const bf16x8* bfd = (const bf16x8*)wfd_hi + lane;
    f32x4 acc[4];
    #pragma unroll
    for (int nt = 0; nt < 4; ++nt) acc[nt] = (f32x4){0.f, 0.f, 0.f, 0.f};
    int sb = m * 9 * 4;
    #pragma unroll 3
    for (int kk = 0; kk < 9; ++kk) {
        bf16x4 wb = *(const bf16x4*)&swv[sb + kk * 4];
        u16x4  o4 = *(const u16x4*)&sov[sb + kk * 4];
        const bf16* p00 = xtb + (((int)o4.x) << 6) + g * 8;
        const bf16* p01 = xtb + (((int)o4.y) << 6) + g * 8;
        const bf16* p10 = xtb + (((int)o4.z) << 6) + g * 8;
        const bf16* p11 = xtb + (((int)o4.w) << 6) + g * 8;
        bf16x8 v00a = *(const bf16x8*)p00, v00b = *(const bf16x8*)(p00 + 32);
        bf16x8 v01a = *(const bf16x8*)p01, v01b = *(const bf16x8*)(p01 + 32);
        bf16x8 v10a = *(const bf16x8*)p10, v10b = *(const bf16x8*)(p10 + 32);
        bf16x8 v11a = *(const bf16x8*)p11, v11b = *(const bf16x8*)(p11 + 32);
        float w00 = (float)wb.x, w01 = (float)wb.y;
        float w10 = (float)wb.z, w11 = (float)wb.w;
        bf16x8 af0, af1;
        #pragma unroll
        for (int j = 0; j < 8; ++j) {
            af0[j] = (bf16)(w00 * (float)v00a[j] + w01 * (float)v01a[j]
                          + w10 * (float)v10a[j] + w11 * (float)v11a[j]);
            af1[j] = (bf16)(w00 * (float)v00b[j] + w01 * (float)v01b[j]
                          + w10 * (float)v10b[j] + w11 * (float)v11b[j]);
        }
        int ks0 = 2 * kk, ks1 = 2 * kk + 1;
        acc[0] = MFMA(af0, bfd[(0 * 18 + ks0) * 64], acc[0]);
        acc[0] = MFMA(af1, bfd[(0 * 18 + ks1) * 64], acc[0]);
        acc[1] = MFMA(af0, bfd[(1 * 18 + ks0) * 64], acc[1]);
        acc[1] = MFMA(af1, bfd[(1 * 18 + ks1) * 64], acc[1]);
        acc[2] = MFMA(af0, bfd[(2 * 18 + ks0) * 64], acc[2]);
        acc[2] = MFMA(af1, bfd[(2 * 18 + ks1) * 64], acc[2]);
        acc[3] = MFMA(af0, bfd[(3 * 18 + ks0) * 64], acc[3]);
        acc[3] = MFMA(af1, bfd[(3 * 18 + ks1) * 64], acc[3]);
    }
    // lane (m,g) reg r holds D[p=g*4+r][o=nt*16+m]
    #pragma unroll
    for (int nt = 0; nt < 4; ++nt) {
        int o = nt * 16 + m;
        float bias = db[o];
        float4 vv = {acc[nt][0] + bias, acc[nt][1] + bias,
                     acc[nt][2] + bias, acc[nt][3] + bias};
        *(float4*)&out[((size_t)(b * 64 + o)) * HW + ho * 128 + wo0 + st * 16 + g * 4] = vv;
    }
}

extern "C" void kernel_launch(void* const* d_in, const int* in_sizes, int n_in,
                              void* d_out, int out_size, void* d_ws, size_t ws_size,
                              hipStream_t stream) {
    const float* x   = (const float*)d_in[0];
    const float* ow  = (const float*)d_in[1];
    const float* ob  = (const float*)d_in[2];
    const float* mw  = (const float*)d_in[3];
    const float* mb  = (const float*)d_in[4];
    const float* db  = (const float*)d_in[6];
    const float* dw  = (const float*)d_in[5];
    float* out = (float*)d_out;

    bf16* xt = (bf16*)d_ws;                         // 4,194,304 bf16 = 8 MB
    bf16* wfd_hi = xt + (size_t)BB * HW * CC;
    bf16* wfd_lo = wfd_hi + 36864;
    bf16* wfo_hi = wfd_lo + 36864;
    bf16* wfo_lo = wfo_hi + 18432;

    k_pre<<<1024 + 216, 256, 0, stream>>>(x, xt, dw, ow, mw, wfd_hi, wfd_lo, wfo_hi, wfo_lo);
    k_fused<<<(BB * HW) / 64, 256, 0, stream>>>(xt, wfo_hi, wfo_lo, wfd_hi, ob, mb, db, out);
}